// Round 1
// baseline (1507.989 us; speedup 1.0000x reference)
//
#include <hip/hip_runtime.h>
#include <math.h>

#define NL   16      // levels
#define NF   2       // features per level
#define RMAX 512
#define R1   (RMAX + 1)          // 513, allocated leading dim
#define HID  128
#define IN_DIM (NL * NF)         // 32

struct ResArg { int r[NL]; };

__global__ __launch_bounds__(256, 2)
void ngp_fused_fp32(const float* __restrict__ x,
                    const float* __restrict__ grids,
                    const float* __restrict__ W1, const float* __restrict__ b1,
                    const float* __restrict__ W2, const float* __restrict__ b2,
                    const float* __restrict__ W3, const float* __restrict__ b3,
                    float* __restrict__ out, int n_pts, ResArg res)
{
    int n = blockIdx.x * blockDim.x + threadIdx.x;
    if (n >= n_pts) return;

    float x0 = x[2 * n + 0];
    float x1 = x[2 * n + 1];

    // ---- multiresolution bilinear gather: feats[l*2 + f] ----
    float feats[IN_DIM];
    #pragma unroll
    for (int l = 0; l < NL; ++l) {
        int   r  = res.r[l];
        float rf = (float)r;                 // matches r.astype(float32)
        float px = x0 * rf, py = x1 * rf;
        float fx = floorf(px), fy = floorf(py);
        int ix0 = (int)fx, iy0 = (int)fy;
        ix0 = min(max(ix0, 0), r);
        iy0 = min(max(iy0, 0), r);
        int ix1 = min(ix0 + 1, r);
        int iy1 = min(iy0 + 1, r);
        float wx = px - fx, wy = py - fy;
        float omx = 1.0f - wx, omy = 1.0f - wy;

        const float2* g = (const float2*)(grids + (size_t)l * (size_t)(R1 * R1 * NF));
        float2 f00 = g[ix0 * R1 + iy0];
        float2 f10 = g[ix1 * R1 + iy0];
        float2 f01 = g[ix0 * R1 + iy1];
        float2 f11 = g[ix1 * R1 + iy1];

        feats[l * NF + 0] = (f00.x * omx + f10.x * wx) * omy + (f01.x * omx + f11.x * wx) * wy;
        feats[l * NF + 1] = (f00.y * omx + f10.y * wx) * omy + (f01.y * omx + f11.y * wx) * wy;
    }

    // ---- layer 1: 32 -> 128, ReLU. h1 kept in VGPRs (all indices static) ----
    float h1v[HID];
    #pragma unroll
    for (int jc = 0; jc < HID / 8; ++jc) {
        float acc[8];
        #pragma unroll
        for (int j = 0; j < 8; ++j) acc[j] = b1[jc * 8 + j];
        #pragma unroll
        for (int k = 0; k < IN_DIM; ++k) {
            float f = feats[k];
            #pragma unroll
            for (int j = 0; j < 8; ++j)
                acc[j] = fmaf(f, W1[k * HID + jc * 8 + j], acc[j]);  // uniform addr -> s_load
        }
        #pragma unroll
        for (int j = 0; j < 8; ++j) h1v[jc * 8 + j] = fmaxf(acc[j], 0.0f);
    }

    // ---- layer 2 (128 -> 128, ReLU) fused with layer 3 (128 -> 1):
    //      h2 never materialized; chunk-of-8 outputs, dot with W3 immediately ----
    float o = 0.0f;
    #pragma unroll 1                      // keep code size bounded; jc is wave-uniform
    for (int jc = 0; jc < HID / 8; ++jc) {
        float acc[8];
        #pragma unroll
        for (int j = 0; j < 8; ++j) acc[j] = b2[jc * 8 + j];
        #pragma unroll
        for (int k = 0; k < HID; ++k) {
            float h = h1v[k];             // static index -> stays in VGPR
            #pragma unroll
            for (int j = 0; j < 8; ++j)
                acc[j] = fmaf(h, W2[k * HID + jc * 8 + j], acc[j]);  // uniform -> s_load
        }
        #pragma unroll
        for (int j = 0; j < 8; ++j)
            o += fmaxf(acc[j], 0.0f) * W3[jc * 8 + j];
    }

    out[n] = o + b3[0];
}

extern "C" void kernel_launch(void* const* d_in, const int* in_sizes, int n_in,
                              void* d_out, int out_size, void* d_ws, size_t ws_size,
                              hipStream_t stream)
{
    const float* x     = (const float*)d_in[0];
    const float* grids = (const float*)d_in[1];
    const float* W1    = (const float*)d_in[2];
    const float* b1    = (const float*)d_in[3];
    const float* W2    = (const float*)d_in[4];
    const float* b2    = (const float*)d_in[5];
    const float* W3    = (const float*)d_in[6];
    const float* b3    = (const float*)d_in[7];
    float* outp        = (float*)d_out;

    int n_pts = in_sizes[0] / 2;

    // Replicate numpy: RES = floor(BASE_RES * growth**arange(L)), growth = (512/16)**(1/15)
    ResArg res;
    double growth = pow(512.0 / 16.0, 1.0 / 15.0);
    for (int l = 0; l < NL; ++l)
        res.r[l] = (int)floor(16.0 * pow(growth, (double)l));

    dim3 block(256);
    dim3 grid((n_pts + 255) / 256);
    hipLaunchKernelGGL(ngp_fused_fp32, grid, block, 0, stream,
                       x, grids, W1, b1, W2, b2, W3, b3, outp, n_pts, res);
}

// Round 2
// 604.549 us; speedup vs baseline: 2.4944x; 2.4944x over previous
//
#include <hip/hip_runtime.h>
#include <math.h>

#define NL 16
#define R1 513                       // (RMAX+1)
#define LVL_STRIDE (R1 * R1 * 2)     // floats per level
#define HID 128
#define IN_DIM 32
#define MT 4                         // M-tiles (of 16 points) per wave-iteration

typedef float f32x4 __attribute__((ext_vector_type(4)));
typedef short s16x8 __attribute__((ext_vector_type(8)));   // 8 bf16 (4 VGPRs)

struct ResArg { int r[NL]; };

static __device__ __forceinline__ unsigned short f2h(float f) {
    __bf16 b = (__bf16)f;                       // RNE f32->bf16
    return __builtin_bit_cast(unsigned short, b);
}
static __device__ __forceinline__ float4 ld16(const float* p) {
    float4 q;                                   // 16B load, 8B-aligned address
    __builtin_memcpy(&q, (const float*)__builtin_assume_aligned((const void*)p, 8), 16);
    return q;
}

__global__ __launch_bounds__(256, 2)
void ngp_mfma(const float* __restrict__ x,
              const float* __restrict__ grids,
              const float* __restrict__ W1, const float* __restrict__ b1,
              const float* __restrict__ W2, const float* __restrict__ b2,
              const float* __restrict__ W3, const float* __restrict__ b3,
              float* __restrict__ out, int n_pts, ResArg res)
{
    // LDS: W1^T 8KB + W2^T 32KB + biases/W3 1.5KB + per-wave h1 tiles 16KB = ~57.6KB -> 2 blocks/CU
    __shared__ unsigned short w1t[IN_DIM * HID];      // [n=128][k=32] bf16, swizzled
    __shared__ unsigned short w2t[HID * HID];         // [n=128][k=128] bf16, swizzled
    __shared__ float b1s[HID], b2s[HID], w3s[HID];
    __shared__ int rs[NL];
    __shared__ unsigned short h1t[4][16 * HID];       // per-wave transpose tile (swizzled)

    const int tid = threadIdx.x;

    // ---- setup: stage weights (transposed, bf16, XOR-swizzled) ----
    for (int idx = tid; idx < IN_DIM * HID; idx += 256) {
        int n = idx & 127, k = idx >> 7;              // W1 global is [k][n], read coalesced
        w1t[(n * IN_DIM + k) ^ ((n & 7) << 3)] = f2h(W1[idx]);
    }
    for (int idx = tid; idx < HID * HID; idx += 256) {
        int n = idx & 127, k = idx >> 7;              // W2 global is [k][n]
        w2t[(n * HID + k) ^ ((n & 7) << 3)] = f2h(W2[idx]);
    }
    if (tid < HID) { b1s[tid] = b1[tid]; b2s[tid] = b2[tid]; w3s[tid] = W3[tid]; }
    if (tid == 0) {
        #pragma unroll
        for (int l = 0; l < NL; ++l) rs[l] = res.r[l];   // static kernarg indices only
    }
    __syncthreads();

    const int lane = tid & 63;
    const int wv   = tid >> 6;
    const int g    = lane >> 4;      // k-slice group (also level group 4g..4g+3)
    const int cl   = lane & 15;      // row/col lane id
    unsigned short* myh1 = h1t[wv];

    // per-lane level tables (levels 4g..4g+3), hoisted out of the main loop
    int lr[4]; float lrf[4]; const float* gp[4];
    #pragma unroll
    for (int lv = 0; lv < 4; ++lv) {
        int L = 4 * g + lv;
        lr[lv]  = rs[L];
        lrf[lv] = (float)lr[lv];
        gp[lv]  = grids + (size_t)L * LVL_STRIDE;
    }

    const int gw = blockIdx.x * 4 + wv;
    const int nw = gridDim.x * 4;
    const float bias3 = b3[0];

    for (int base = gw * (MT * 16); base < n_pts; base += nw * (MT * 16)) {

        // ---- multires bilinear gather -> layer-1 A-fragments (in-register) ----
        s16x8 fa[MT];
        #pragma unroll
        for (int m = 0; m < MT; ++m) {
            int pt = base + m * 16 + cl;
            pt = min(pt, n_pts - 1);
            float2 xv = *(const float2*)(x + 2 * pt);
            #pragma unroll
            for (int lv = 0; lv < 4; ++lv) {
                int   r  = lr[lv];
                float px = xv.x * lrf[lv], py = xv.y * lrf[lv];
                float fx = floorf(px), fy = floorf(py);
                int ix0 = (int)fx; ix0 = max(0, min(ix0, r));
                int iy0 = (int)fy; iy0 = max(0, min(iy0, r));
                int ix1 = min(ix0 + 1, r);
                float wx = px - fx, wy = py - fy;
                float omx = 1.f - wx, omy = 1.f - wy;
                int iyl = min(iy0, r - 1);            // 16B load covers (iyl, iyl+1)
                float4 q0 = ld16(gp[lv] + (size_t)(ix0 * R1 + iyl) * 2);
                float4 q1 = ld16(gp[lv] + (size_t)(ix1 * R1 + iyl) * 2);
                bool hi = (iy0 != iyl);               // only when iy0 == r
                float f00x = hi ? q0.z : q0.x, f00y = hi ? q0.w : q0.y;
                float f10x = hi ? q1.z : q1.x, f10y = hi ? q1.w : q1.y;
                float f01x = q0.z, f01y = q0.w;
                float f11x = q1.z, f11y = q1.w;
                float vx = (f00x * omx + f10x * wx) * omy + (f01x * omx + f11x * wx) * wy;
                float vy = (f00y * omx + f10y * wx) * omy + (f01y * omx + f11y * wx) * wy;
                fa[m][2 * lv + 0] = (short)f2h(vx);   // k = 8g + 2*lv + f
                fa[m][2 * lv + 1] = (short)f2h(vy);
            }
        }

        // ---- layer 1: D[pt][neuron] = feats @ W1 + b1 (K=32, one MFMA step) ----
        f32x4 acc1[MT][8];
        #pragma unroll
        for (int t = 0; t < 8; ++t) {
            int n = t * 16 + cl;
            float bb = b1s[n];
            s16x8 w1f = *(const s16x8*)&w1t[(n * IN_DIM + 8 * g) ^ ((n & 7) << 3)];
            #pragma unroll
            for (int m = 0; m < MT; ++m) {
                f32x4 c = {bb, bb, bb, bb};
                acc1[m][t] = __builtin_amdgcn_mfma_f32_16x16x32_bf16(fa[m], w1f, c, 0, 0, 0);
            }
        }

        // ---- relu -> bf16 -> per-wave LDS transpose -> layer-2 A-frags ----
        s16x8 ha[MT][4];
        #pragma unroll
        for (int m = 0; m < MT; ++m) {
            #pragma unroll
            for (int t = 0; t < 8; ++t) {
                int col = t * 16 + cl;
                f32x4 v = acc1[m][t];
                #pragma unroll
                for (int j = 0; j < 4; ++j) {
                    int row = 4 * g + j;              // D row = point-in-tile
                    myh1[(row * HID + col) ^ ((row & 7) << 3)] = f2h(fmaxf(v[j], 0.f));
                }
            }
            #pragma unroll
            for (int s = 0; s < 4; ++s)               // A-frag: row=cl, k=32s+8g..+7
                ha[m][s] = *(const s16x8*)&myh1[(cl * HID + s * 32 + 8 * g) ^ ((cl & 7) << 3)];
        }

        // ---- layer 2: K=128 in 4 MFMA steps ----
        f32x4 acc2[MT][8];
        #pragma unroll
        for (int t = 0; t < 8; ++t) {
            float bb = b2s[t * 16 + cl];
            #pragma unroll
            for (int m = 0; m < MT; ++m) { f32x4 c = {bb, bb, bb, bb}; acc2[m][t] = c; }
        }
        #pragma unroll
        for (int s = 0; s < 4; ++s) {
            #pragma unroll
            for (int t = 0; t < 8; ++t) {
                int n = t * 16 + cl;
                s16x8 w2f = *(const s16x8*)&w2t[(n * HID + s * 32 + 8 * g) ^ ((n & 7) << 3)];
                #pragma unroll
                for (int m = 0; m < MT; ++m)
                    acc2[m][t] = __builtin_amdgcn_mfma_f32_16x16x32_bf16(ha[m][s], w2f, acc2[m][t], 0, 0, 0);
            }
        }

        // ---- layer 3 (+ relu) fused epilogue: per-lane partials, 16-lane reduce ----
        #pragma unroll
        for (int m = 0; m < MT; ++m) {
            float o0 = 0.f, o1 = 0.f, o2 = 0.f, o3 = 0.f;
            #pragma unroll
            for (int t = 0; t < 8; ++t) {
                float w3v = w3s[t * 16 + cl];
                f32x4 v = acc2[m][t];
                o0 += fmaxf(v.x, 0.f) * w3v;
                o1 += fmaxf(v.y, 0.f) * w3v;
                o2 += fmaxf(v.z, 0.f) * w3v;
                o3 += fmaxf(v.w, 0.f) * w3v;
            }
            #pragma unroll
            for (int mask = 1; mask < 16; mask <<= 1) {
                o0 += __shfl_xor(o0, mask);
                o1 += __shfl_xor(o1, mask);
                o2 += __shfl_xor(o2, mask);
                o3 += __shfl_xor(o3, mask);
            }
            if (cl < 4) {
                int row = base + m * 16 + 4 * g + cl;
                float val = (cl == 0) ? o0 : (cl == 1) ? o1 : (cl == 2) ? o2 : o3;
                if (row < n_pts) out[row] = val + bias3;
            }
        }
    }
}

extern "C" void kernel_launch(void* const* d_in, const int* in_sizes, int n_in,
                              void* d_out, int out_size, void* d_ws, size_t ws_size,
                              hipStream_t stream)
{
    const float* x     = (const float*)d_in[0];
    const float* grids = (const float*)d_in[1];
    const float* W1    = (const float*)d_in[2];
    const float* b1    = (const float*)d_in[3];
    const float* W2    = (const float*)d_in[4];
    const float* b2    = (const float*)d_in[5];
    const float* W3    = (const float*)d_in[6];
    const float* b3    = (const float*)d_in[7];
    float* outp        = (float*)d_out;

    int n_pts = in_sizes[0] / 2;

    ResArg res;
    double growth = pow(512.0 / 16.0, 1.0 / 15.0);
    for (int l = 0; l < NL; ++l)
        res.r[l] = (int)floor(16.0 * pow(growth, (double)l));

    dim3 block(256);
    dim3 grid(512);                       // 2 blocks/CU, grid-stride over 32768 point-groups
    hipLaunchKernelGGL(ngp_mfma, grid, block, 0, stream,
                       x, grids, W1, b1, W2, b2, W3, b3, outp, n_pts, res);
}